// Round 1
// baseline (13626.022 us; speedup 1.0000x reference)
//
#include <hip/hip_runtime.h>
#include <cmath>

#define NL 8
#define NR 8
#define DIM 768
#define LTOK 512
#define RTOK 512
#define EDIM 12288   // (NL+NR)*DIM

// ---------------------------------------------------------------------------
// Kernel 1: token-matching scores.  scores[i][j] = Wl . highway(|l_i - r_j|)
// (lin_tok bias omitted: constant shift, irrelevant for argmax)
// Block: 256 threads = 16 i x 16 j pair tile, one pair per thread.
// Outer loop over output-dim chunks of DC=32; K staged in chunks of KC=128.
// ---------------------------------------------------------------------------
#define DC 32
#define KC 128

__global__ __launch_bounds__(256) void scores_kernel(
    const float* __restrict__ Lg, const float* __restrict__ Rg,
    const float* __restrict__ Wn, const float* __restrict__ Wg,
    const float* __restrict__ bn, const float* __restrict__ bg,
    const float* __restrict__ Wl,
    float* __restrict__ scores)
{
    __shared__ float lT[16][KC + 4];   // +4 words pad -> <=2-way bank alias (free)
    __shared__ float rT[16][KC + 4];
    __shared__ float wnT[KC][DC];      // broadcast reads, no conflict
    __shared__ float wgT[KC][DC];

    const int t  = threadIdx.x;
    const int i0 = blockIdx.x * 16;
    const int j0 = blockIdx.y * 16;
    const int ti = t >> 4;
    const int tj = t & 15;

    const float* lrow = Lg + (i0 + ti) * DIM;
    const float* rrow = Rg + (j0 + tj) * DIM;

    float score = 0.f;

    for (int dc = 0; dc < DIM; dc += DC) {
        float hacc[DC], gacc[DC];
#pragma unroll
        for (int d = 0; d < DC; ++d) { hacc[d] = 0.f; gacc[d] = 0.f; }

        for (int k0 = 0; k0 < DIM; k0 += KC) {
            __syncthreads();
            // stage l/r tiles: 16 x KC each (512 float4 per matrix, 2/thread)
#pragma unroll
            for (int r = 0; r < 2; ++r) {
                int idx = t + r * 256;          // float4 index 0..511
                int row = idx >> 5;             // 16 rows
                int c4  = (idx & 31) << 2;      // 32 float4 per row
                float4 lv = *(const float4*)(Lg + (i0 + row) * DIM + k0 + c4);
                float4 rv = *(const float4*)(Rg + (j0 + row) * DIM + k0 + c4);
                *(float4*)&lT[row][c4] = lv;
                *(float4*)&rT[row][c4] = rv;
            }
            // stage weight slabs: KC x DC each (1024 float4, 4/thread)
#pragma unroll
            for (int r = 0; r < 4; ++r) {
                int idx = t + r * 256;          // float4 index 0..1023
                int row = idx >> 3;             // KC rows
                int c4  = (idx & 7) << 2;       // 8 float4 per row
                *(float4*)&wnT[row][c4] = *(const float4*)(Wn + (size_t)(k0 + row) * DIM + dc + c4);
                *(float4*)&wgT[row][c4] = *(const float4*)(Wg + (size_t)(k0 + row) * DIM + dc + c4);
            }
            __syncthreads();

            for (int k = 0; k < KC; ++k) {
                float c = fabsf(lT[ti][k] - rT[tj][k]);
#pragma unroll
                for (int d = 0; d < DC; ++d) {
                    hacc[d] = fmaf(c, wnT[k][d], hacc[d]);
                    gacc[d] = fmaf(c, wgT[k][d], gacc[d]);
                }
            }
        }

        // nonlinearity + score accumulation for this output chunk
#pragma unroll
        for (int d = 0; d < DC; ++d) {
            float h  = fmaxf(hacc[d] + bn[dc + d], 0.f);
            float gv = 1.f / (1.f + expf(-(gacc[d] + bg[dc + d])));
            float c  = fabsf(lrow[dc + d] - rrow[dc + d]);
            float hw = gv * h + (1.f - gv) * c;
            score = fmaf(hw, Wl[dc + d], score);
        }
    }

    scores[(i0 + ti) * RTOK + (j0 + tj)] = score;
}

// ---------------------------------------------------------------------------
// Kernel 2: argmax per row (left tokens) and per column (right tokens).
// First-occurrence tie-break to match np.argmax.
// ---------------------------------------------------------------------------
__global__ __launch_bounds__(64) void argmax_kernel(
    const float* __restrict__ scores, int* __restrict__ idxL, int* __restrict__ idxR)
{
    const int b = blockIdx.x;          // 0..511 rows, 512..1023 cols
    const int t = threadIdx.x;
    const bool isRow = (b < LTOK);
    const int  n = b & (LTOK - 1);

    float best = -INFINITY;
    int   bidx = 0x7fffffff;
    for (int s = t; s < 512; s += 64) {
        float v = isRow ? scores[n * RTOK + s] : scores[s * RTOK + n];
        if (v > best) { best = v; bidx = s; }
    }
#pragma unroll
    for (int off = 32; off; off >>= 1) {
        float ob = __shfl_down(best, off);
        int   oi = __shfl_down(bidx, off);
        if (ob > best || (ob == best && oi < bidx)) { best = ob; bidx = oi; }
    }
    if (t == 0) (isRow ? idxL : idxR)[n] = bidx;
}

// ---------------------------------------------------------------------------
// Kernel 3: gather chosen cmp rows.
// ---------------------------------------------------------------------------
__global__ __launch_bounds__(256) void build_cmp_kernel(
    const float* __restrict__ Lg, const float* __restrict__ Rg,
    const int* __restrict__ idxL, const int* __restrict__ idxR,
    float* __restrict__ lcmp, float* __restrict__ rcmp)
{
    const int b = blockIdx.x;
    const int t = threadIdx.x;
    if (b < LTOK) {
        const float* a = Lg + b * DIM;
        const float* c = Rg + idxL[b] * DIM;
        for (int d = t; d < DIM; d += 256) lcmp[b * DIM + d] = fabsf(a[d] - c[d]);
    } else {
        const int j = b - LTOK;
        const float* a = Rg + j * DIM;
        const float* c = Lg + idxR[j] * DIM;
        for (int d = t; d < DIM; d += 256) rcmp[j * DIM + d] = fabsf(a[d] - c[d]);
    }
}

// ---------------------------------------------------------------------------
// Kernel 4: attribute matching (ragged segment softmax + weighted cmp sum).
// One block per (side, attr).  Writes directly into concat layout x[16*768].
// ---------------------------------------------------------------------------
__global__ __launch_bounds__(256) void attr_match_kernel(
    const float* __restrict__ Lg, const float* __restrict__ Rg,
    const float* __restrict__ lcmp, const float* __restrict__ rcmp,
    const int* __restrict__ lensL, const int* __restrict__ lensR,
    const float* __restrict__ embL, const float* __restrict__ embR,
    const float* __restrict__ emptyRes,
    float* __restrict__ x)
{
    __shared__ float logits[512];
    __shared__ float red[256];

    const int b    = blockIdx.x;
    const int side = b >> 3;
    const int a    = b & 7;
    const int t    = threadIdx.x;

    const int*   lens = side ? lensR : lensL;
    const float* toks = side ? Rg   : Lg;
    const float* cmp  = side ? rcmp : lcmp;
    const float* femb = (side ? embR : embL) + a * DIM;
    float* outp = x + (side * 8 + a) * DIM;

    int start = 0;
    for (int q = 0; q < a; ++q) start += lens[q];
    const int len = lens[a];

    if (len == 0) {
        for (int d = t; d < DIM; d += 256) outp[d] = emptyRes[d];
        return;
    }

    // per-token logits: dot(token, attr_emb)
    for (int tok = t; tok < len; tok += 256) {
        const float* tr = toks + (start + tok) * DIM;
        float s = 0.f;
        for (int d = 0; d < DIM; ++d) s = fmaf(tr[d], femb[d], s);
        logits[tok] = s;
    }
    __syncthreads();

    // max
    float m = -INFINITY;
    for (int tok = t; tok < len; tok += 256) m = fmaxf(m, logits[tok]);
    red[t] = m; __syncthreads();
    for (int off = 128; off; off >>= 1) {
        if (t < off) red[t] = fmaxf(red[t], red[t + off]);
        __syncthreads();
    }
    m = red[0]; __syncthreads();

    // exp + sum (store exp back into logits)
    float sum = 0.f;
    for (int tok = t; tok < len; tok += 256) {
        float e = expf(logits[tok] - m);
        logits[tok] = e;
        sum += e;
    }
    red[t] = sum; __syncthreads();
    for (int off = 128; off; off >>= 1) {
        if (t < off) red[t] += red[t + off];
        __syncthreads();
    }
    const float inv = 1.f / red[0];
    __syncthreads();

    // weighted sum of cmp rows
    for (int d = t; d < DIM; d += 256) {
        float acc = 0.f;
        for (int tok = 0; tok < len; ++tok)
            acc = fmaf(logits[tok] * inv, cmp[(start + tok) * DIM + d], acc);
        outp[d] = acc;
    }
}

// ---------------------------------------------------------------------------
// Kernel 5: entity highway matvec partials (split-K, deterministic).
// grid (12 out-blocks x 32 in-slabs x 2 mats); each thread: 4 outputs (float4).
// ---------------------------------------------------------------------------
__global__ __launch_bounds__(256) void ent_partial_kernel(
    const float* __restrict__ Wn, const float* __restrict__ Wg,
    const float* __restrict__ x, float* __restrict__ partial)
{
    __shared__ float xs[384];
    const int ob   = blockIdx.x;   // 12
    const int slab = blockIdx.y;   // 32
    const int mat  = blockIdx.z;   // 2
    const float* W = mat ? Wg : Wn;
    const int t  = threadIdx.x;
    const int o0 = ob * 1024 + t * 4;
    const int in0 = slab * 384;

    for (int i = t; i < 384; i += 256) xs[i] = x[in0 + i];
    __syncthreads();

    float4 acc = {0.f, 0.f, 0.f, 0.f};
    for (int in = 0; in < 384; ++in) {
        const float  xv = xs[in];
        const float4 w  = *(const float4*)(W + (size_t)(in0 + in) * EDIM + o0);
        acc.x = fmaf(xv, w.x, acc.x);
        acc.y = fmaf(xv, w.y, acc.y);
        acc.z = fmaf(xv, w.z, acc.z);
        acc.w = fmaf(xv, w.w, acc.w);
    }
    *(float4*)(partial + ((size_t)mat * 32 + slab) * EDIM + o0) = acc;
}

// ---------------------------------------------------------------------------
// Kernel 6: reduce the 32 split-K partials.
// ---------------------------------------------------------------------------
__global__ __launch_bounds__(256) void ent_reduce_kernel(
    const float* __restrict__ partial, float* __restrict__ hsum)
{
    const int mat = blockIdx.y;
    const int o   = blockIdx.x * 1024 + threadIdx.x * 4;
    float4 acc = {0.f, 0.f, 0.f, 0.f};
    for (int s = 0; s < 32; ++s) {
        const float4 p = *(const float4*)(partial + ((size_t)mat * 32 + s) * EDIM + o);
        acc.x += p.x; acc.y += p.y; acc.z += p.z; acc.w += p.w;
    }
    *(float4*)(hsum + (size_t)mat * EDIM + o) = acc;
}

// ---------------------------------------------------------------------------
// Kernel 7: entity highway epilogue + final linear + softmax.
// ---------------------------------------------------------------------------
__global__ __launch_bounds__(256) void finalize_kernel(
    const float* __restrict__ hsum, const float* __restrict__ x,
    const float* __restrict__ bn, const float* __restrict__ bg,
    const float* __restrict__ Wl2, const float* __restrict__ bl2,
    float* __restrict__ out)
{
    __shared__ float r0[256], r1[256];
    const int t = threadIdx.x;
    float l0 = 0.f, l1 = 0.f;
    for (int d = t; d < EDIM; d += 256) {
        float h  = fmaxf(hsum[d] + bn[d], 0.f);
        float gv = 1.f / (1.f + expf(-(hsum[EDIM + d] + bg[d])));
        float hw = gv * h + (1.f - gv) * x[d];
        l0 = fmaf(hw, Wl2[d * 2 + 0], l0);
        l1 = fmaf(hw, Wl2[d * 2 + 1], l1);
    }
    r0[t] = l0; r1[t] = l1; __syncthreads();
    for (int off = 128; off; off >>= 1) {
        if (t < off) { r0[t] += r0[t + off]; r1[t] += r1[t + off]; }
        __syncthreads();
    }
    if (t == 0) {
        float a = r0[0] + bl2[0];
        float b = r1[0] + bl2[1];
        float m  = fmaxf(a, b);
        float ea = expf(a - m), eb = expf(b - m);
        float inv = 1.f / (ea + eb);
        out[0] = ea * inv;
        out[1] = eb * inv;
    }
}

// ---------------------------------------------------------------------------
extern "C" void kernel_launch(void* const* d_in, const int* in_sizes, int n_in,
                              void* d_out, int out_size, void* d_ws, size_t ws_size,
                              hipStream_t stream)
{
    const float* Lg     = (const float*)d_in[0];
    const float* Rg     = (const float*)d_in[1];
    const int*   lensL  = (const int*)  d_in[2];
    const int*   lensR  = (const int*)  d_in[3];
    const float* tWn    = (const float*)d_in[4];
    const float* tbn    = (const float*)d_in[5];
    const float* tWg    = (const float*)d_in[6];
    const float* tbg    = (const float*)d_in[7];
    const float* tWl    = (const float*)d_in[8];
    // d_in[9] = lin_tok_b : constant score shift, irrelevant to argmax
    const float* embL   = (const float*)d_in[10];
    const float* embR   = (const float*)d_in[11];
    const float* eWn    = (const float*)d_in[12];
    const float* ebn    = (const float*)d_in[13];
    const float* eWg    = (const float*)d_in[14];
    const float* ebg    = (const float*)d_in[15];
    const float* eWl    = (const float*)d_in[16];
    const float* ebl    = (const float*)d_in[17];
    const float* emptyR = (const float*)d_in[18];
    float* out = (float*)d_out;

    // workspace layout
    char* ws = (char*)d_ws;
    float* scores  = (float*)(ws);                               // 512*512
    int*   idxL    = (int*)  (ws + (size_t)1048576);             // 512
    int*   idxR    = idxL + 512;                                 // 512
    float* lcmp    = (float*)(ws + (size_t)1048576 + 4096);      // 512*768
    float* rcmp    = lcmp + (size_t)LTOK * DIM;                  // 512*768
    float* xcat    = rcmp + (size_t)RTOK * DIM;                  // 12288
    float* partial = xcat + EDIM;                                // 2*32*12288
    float* hsum    = partial + (size_t)2 * 32 * EDIM;            // 2*12288

    scores_kernel<<<dim3(LTOK / 16, RTOK / 16), 256, 0, stream>>>(
        Lg, Rg, tWn, tWg, tbn, tbg, tWl, scores);

    argmax_kernel<<<dim3(LTOK + RTOK), 64, 0, stream>>>(scores, idxL, idxR);

    build_cmp_kernel<<<dim3(LTOK + RTOK), 256, 0, stream>>>(
        Lg, Rg, idxL, idxR, lcmp, rcmp);

    attr_match_kernel<<<dim3(16), 256, 0, stream>>>(
        Lg, Rg, lcmp, rcmp, lensL, lensR, embL, embR, emptyR, xcat);

    ent_partial_kernel<<<dim3(EDIM / 1024, 32, 2), 256, 0, stream>>>(
        eWn, eWg, xcat, partial);

    ent_reduce_kernel<<<dim3(EDIM / 1024, 2), 256, 0, stream>>>(partial, hsum);

    finalize_kernel<<<dim3(1), 256, 0, stream>>>(
        hsum, xcat, ebn, ebg, eWl, ebl, out);
}